// Round 7
// baseline (13139.473 us; speedup 1.0000x reference)
//
#include <hip/hip_runtime.h>
#include <hip/hip_fp16.h>
#include <math.h>

#define BB 32
#define LAV 256
#define LCV 256
#define DV 300
#define HV 256
#define G3 768   // 3*H

typedef _Float16 f16x2 __attribute__((ext_vector_type(2)));
union F4H8 { float4 f4; f16x2 h2[4]; };
union U2H4 { uint2 u2; f16x2 h2[2]; };

// ---------- fast math helpers ----------
static __device__ __forceinline__ float rcp_(float x) { return __builtin_amdgcn_rcpf(x); }
static __device__ __forceinline__ float sigm(float x) { return rcp_(1.f + __expf(-x)); }
static __device__ __forceinline__ float tanh_(float x) { return 1.f - 2.f * rcp_(1.f + __expf(2.f * x)); }

// ---------- weight packing ----------
// c0: WT_a  [300][768] = W_ih_a^T (fp32)
// c1: WT_cx [300][768] = W_ih_c[:,:300]^T (fp32)
// c2: Whha4 [64 k4][768 j][4 c] fp32 quad-k pack of W_hh_a^T (anchor, fp32)
// c3: WqP   half [128 k2][256 m][2 e] = Wq[2*k2+e][m]
// c4: WrzHH half rz-hidden [64 q6][512 j][2 s][2 e]: kq=q6>>5,i2=q6&31,
//     k2=kq*64+2*i2+s, k=2*k2+e (0..255) -> W_hh_c[j][k]
// c5: WrzCH half rz-ctx    [64 q6][512 j][2 s][2 e]: k2=128+kq*64+2*i2+s,
//     kc=2*k2+e-256 -> W_ih_c[j][300+kc]
// c6: WnHH  half n-hidden  [64 p][256 jn][2 s][2 e]: sq=p>>4,i2=p&15,
//     k=2*(sq*32+2*i2+s)+e -> W_hh_c[512+jn][k]
// c7: WnCH  half n-ctx     same decode -> W_ih_c[512+jn][300+k]
__global__ void prep_pack(const float* __restrict__ W_ih_a, const float* __restrict__ W_ih_c,
                          const float* __restrict__ W_hh_a, const float* __restrict__ W_hh_c,
                          const float* __restrict__ Wq,
                          float* __restrict__ WT_a, float* __restrict__ WT_cx,
                          float* __restrict__ Whha4, __half* __restrict__ WqP,
                          __half* __restrict__ WrzHH, __half* __restrict__ WrzCH,
                          __half* __restrict__ WnHH, __half* __restrict__ WnCH)
{
    int i = blockIdx.x * 256 + threadIdx.x;
    switch (blockIdx.y) {
    case 0: if (i < 230400) { int k = i / 768, n = i % 768; WT_a[i] = W_ih_a[n * 300 + k]; } break;
    case 1: if (i < 230400) { int k = i / 768, n = i % 768; WT_cx[i] = W_ih_c[n * 556 + k]; } break;
    case 2: if (i < 196608) { int cc = i & 3, j = (i >> 2) % 768, k4 = (i >> 2) / 768;
            Whha4[i] = W_hh_a[j * 256 + k4 * 4 + cc]; } break;
    case 3: if (i < 65536) { int e = i & 1, r = i >> 1, m = r & 255, k2 = r >> 8;
            WqP[i] = __float2half(Wq[(2 * k2 + e) * 256 + m]); } break;
    case 4: if (i < 131072) { int e = i & 1, s = (i >> 1) & 1, r = i >> 2, j = r & 511, q6 = r >> 9;
            int kq = q6 >> 5, i2 = q6 & 31;
            int k2 = kq * 64 + 2 * i2 + s;
            WrzHH[i] = __float2half(W_hh_c[j * 256 + 2 * k2 + e]); } break;
    case 5: if (i < 131072) { int e = i & 1, s = (i >> 1) & 1, r = i >> 2, j = r & 511, q6 = r >> 9;
            int kq = q6 >> 5, i2 = q6 & 31;
            int k2 = 128 + kq * 64 + 2 * i2 + s;
            int kc = 2 * k2 + e - 256;
            WrzCH[i] = __float2half(W_ih_c[j * 556 + 300 + kc]); } break;
    case 6: if (i < 65536) { int e = i & 1, s = (i >> 1) & 1, r = i >> 2, jn = r & 255, p = r >> 8;
            int sq = p >> 4, i2 = p & 15;
            int k = 2 * (sq * 32 + 2 * i2 + s) + e;
            WnHH[i] = __float2half(W_hh_c[(512 + jn) * 256 + k]); } break;
    case 7: if (i < 65536) { int e = i & 1, s = (i >> 1) & 1, r = i >> 2, jn = r & 255, p = r >> 8;
            int sq = p >> 4, i2 = p & 15;
            int k = 2 * (sq * 32 + 2 * i2 + s) + e;
            WnCH[i] = __float2half(W_ih_c[(512 + jn) * 556 + 300 + k]); } break;
    }
}

// ---------- tiled fp32 GEMM ----------
// MODE 0: Cout[m*N+n] = acc + bias[n]                         (GI precompute)
// MODE 1: ((half*)Cout)[(b*256+h)*256+l] = clamp(tanh(acc))   (keys -> T)
template <int MODE>
__global__ __launch_bounds__(256) void gemm_tile(
    const float* __restrict__ X, const int* __restrict__ gidx, int ldx,
    const float* __restrict__ Wt, int K, int Nn,
    const float* __restrict__ bias, float* __restrict__ Cout)
{
    __shared__ __align__(16) float As[32][68];
    __shared__ __align__(16) float Bs[32][68];
    __shared__ int toks[64];
    int tid = threadIdx.x;
    int m0 = blockIdx.x * 64, n0 = blockIdx.y * 64;
    if (tid < 64) {
        int m = m0 + tid;
        if (gidx) { int t = m >> 5, b = m & 31; toks[tid] = gidx[b * LAV + t]; }
        else toks[tid] = m;
    }
    __syncthreads();
    float acc[4][4] = {};
    int tx = tid & 15, ty = tid >> 4;
    for (int k0 = 0; k0 < K; k0 += 32) {
        {
            int r = tid >> 2, cc = (tid & 3) * 8;
            const float* src = X + (size_t)toks[r] * ldx + k0 + cc;
            float4 v0 = {0.f,0.f,0.f,0.f}, v1 = {0.f,0.f,0.f,0.f};
            if (k0 + cc + 3 < K) v0 = *(const float4*)src;
            if (k0 + cc + 7 < K) v1 = *(const float4*)(src + 4);
            As[cc+0][r]=v0.x; As[cc+1][r]=v0.y; As[cc+2][r]=v0.z; As[cc+3][r]=v0.w;
            As[cc+4][r]=v1.x; As[cc+5][r]=v1.y; As[cc+6][r]=v1.z; As[cc+7][r]=v1.w;
        }
        {
            int kr = tid >> 4, c4 = (tid & 15) * 4;
            #pragma unroll
            for (int p = 0; p < 2; ++p) {
                float4 v = {0.f,0.f,0.f,0.f};
                int kg = k0 + kr + p * 16;
                if (kg < K) v = *(const float4*)(Wt + (size_t)kg * Nn + n0 + c4);
                *(float4*)&Bs[kr + p * 16][c4] = v;
            }
        }
        __syncthreads();
        #pragma unroll 8
        for (int kk = 0; kk < 32; ++kk) {
            float4 a4 = *(const float4*)&As[kk][ty * 4];
            float4 b4 = *(const float4*)&Bs[kk][tx * 4];
            acc[0][0]=fmaf(a4.x,b4.x,acc[0][0]); acc[0][1]=fmaf(a4.x,b4.y,acc[0][1]);
            acc[0][2]=fmaf(a4.x,b4.z,acc[0][2]); acc[0][3]=fmaf(a4.x,b4.w,acc[0][3]);
            acc[1][0]=fmaf(a4.y,b4.x,acc[1][0]); acc[1][1]=fmaf(a4.y,b4.y,acc[1][1]);
            acc[1][2]=fmaf(a4.y,b4.z,acc[1][2]); acc[1][3]=fmaf(a4.y,b4.w,acc[1][3]);
            acc[2][0]=fmaf(a4.z,b4.x,acc[2][0]); acc[2][1]=fmaf(a4.z,b4.y,acc[2][1]);
            acc[2][2]=fmaf(a4.z,b4.z,acc[2][2]); acc[2][3]=fmaf(a4.z,b4.w,acc[2][3]);
            acc[3][0]=fmaf(a4.w,b4.x,acc[3][0]); acc[3][1]=fmaf(a4.w,b4.y,acc[3][1]);
            acc[3][2]=fmaf(a4.w,b4.z,acc[3][2]); acc[3][3]=fmaf(a4.w,b4.w,acc[3][3]);
        }
        __syncthreads();
    }
    if (MODE == 0) {
        float4 bz = *(const float4*)&bias[n0 + tx * 4];
        #pragma unroll
        for (int i = 0; i < 4; ++i) {
            int m = m0 + ty * 4 + i;
            float4 o = { acc[i][0] + bz.x, acc[i][1] + bz.y, acc[i][2] + bz.z, acc[i][3] + bz.w };
            *(float4*)&Cout[(size_t)m * Nn + n0 + tx * 4] = o;
        }
    } else {
        __half* TH = (__half*)Cout;
        #pragma unroll
        for (int i = 0; i < 4; ++i) {
            int m = m0 + ty * 4 + i;
            int b_ = m >> 8, l = m & 255;
            #pragma unroll
            for (int j = 0; j < 4; ++j) {
                int h = n0 + tx * 4 + j;
                float tv = tanh_(acc[i][j]);
                tv = fminf(fmaxf(tv, -0.999511719f), 0.999511719f);  // keep |T|<1 in fp16 (rcp guard)
                TH[((size_t)(b_ * 256 + h)) * 256 + l] = __float2half(tv);
            }
        }
    }
}

// ---------- anchor GRU: one WG per batch element (fp32, R3-proven) ----------
__global__ __launch_bounds__(384) void anchor_rnn(
    const float* __restrict__ GI, const int* __restrict__ lens,
    const float* __restrict__ bhh, const float* __restrict__ Whh4,
    float* __restrict__ AO, __half* __restrict__ AOH,
    float* __restrict__ hid, float* __restrict__ outp)
{
    int bid = blockIdx.x, tid = threadIdx.x;
    __shared__ __align__(16) float hs[256];
    __shared__ float gh[768];
    if (tid < 256) hs[tid] = 0.f;
    float sum = 0.f;
    int len = lens[bid];
    const float4* W4 = (const float4*)Whh4;
    const float4* hs4 = (const float4*)hs;
    __syncthreads();
    for (int t = 0; t < LAV; ++t) {
        {
            int j0 = tid, j1 = tid + 384;
            float a0=0.f,a1=0.f,a2=0.f,a3=0.f;
            #pragma unroll 8
            for (int k4 = 0; k4 < 64; ++k4) {
                float4 h4 = hs4[k4];
                float4 w0 = W4[k4 * 768 + j0];
                float4 w1 = W4[k4 * 768 + j1];
                a0=fmaf(w0.x,h4.x,a0); a1=fmaf(w0.y,h4.y,a1); a0=fmaf(w0.z,h4.z,a0); a1=fmaf(w0.w,h4.w,a1);
                a2=fmaf(w1.x,h4.x,a2); a3=fmaf(w1.y,h4.y,a3); a2=fmaf(w1.z,h4.z,a2); a3=fmaf(w1.w,h4.w,a3);
            }
            gh[j0] = a0 + a1 + bhh[j0];
            gh[j1] = a2 + a3 + bhh[j1];
        }
        __syncthreads();
        if (tid < 256) {
            const float* gi = GI + ((size_t)t * BB + bid) * G3;
            float gir = gi[tid], giz = gi[256 + tid], gin = gi[512 + tid];
            float r = sigm(gir + gh[tid]);
            float z = sigm(giz + gh[256 + tid]);
            float n = tanh_(fmaf(r, gh[512 + tid], gin));
            float hk = hs[tid];
            float hn = (1.f - z) * n + z * hk;
            bool valid = (t < len);
            float hnew = valid ? hn : hk;
            hs[tid] = hnew;
            float ov = valid ? hn : 0.f;
            AO[((size_t)bid * LAV + t) * HV + tid] = ov;
            AOH[((size_t)bid * LAV + t) * HV + tid] = __float2half(ov);
            sum += ov;
        }
        __syncthreads();
    }
    if (tid < 256) {
        outp[bid * HV + tid] = sum / (float)len;
        hid[bid * HV + tid] = hs[tid];
    }
}

// ---------- candidate GRU + attention: one WG/batch; all weights streamed, Wq in LDS ----------
__global__ __launch_bounds__(1024) void cand_rnn(
    const float* __restrict__ GI, const int* __restrict__ lens,
    const float* __restrict__ bhh, const __half* __restrict__ WrzHH,
    const __half* __restrict__ WrzCH, const __half* __restrict__ WnHH,
    const __half* __restrict__ WnCH, const __half* __restrict__ WqP,
    const float* __restrict__ v_att, const __half* __restrict__ AOH,
    const __half* __restrict__ TH, const float* __restrict__ hid,
    float* __restrict__ outp)
{
    __shared__ __align__(16) __half WqS[65536];      // 128 KB: [k2][m] f16x2 pairs
    __shared__ __align__(16) float redA[1024];
    __shared__ __align__(16) float redB[1024];
    __shared__ __align__(16) float redC[1024];
    __shared__ __align__(16) float redD[1024];
    __shared__ __align__(16) f16x2 x2[256];          // [h pairs 128 ; ctx pairs 128]
    __shared__ __align__(16) float hs[256];
    __shared__ float vls[256];
    __shared__ float attn[256];
    __shared__ __align__(16) float4 tqv[256];        // {tq, v*tq, v, 0}
    __shared__ float wred[8];

    int tid = threadIdx.x;
    int b = blockIdx.x;
    int len = lens[b];

    const __half* TH_b  = TH + (size_t)b * 65536;
    const __half* AOH_b = AOH + (size_t)b * 65536;

    // ---- LDS preload: Wq + state ----
    {
        const float4* s = (const float4*)WqP;
        float4* d = (float4*)WqS;
        for (int u = tid; u < 8192; u += 1024) d[u] = s[u];
    }
    if (tid < 256) { hs[tid] = hid[b * HV + tid]; vls[tid] = v_att[tid]; }
    __syncthreads();
    if (tid < 128) {
        f16x2 v = { (_Float16)hs[2 * tid], (_Float16)hs[2 * tid + 1] };
        x2[tid] = v;
    }
    __syncthreads();

    float csum = 0.f;

    for (int t = 0; t < LCV; ++t) {
        { // A1: q partials (Wq from LDS), 4-way k-split
            int m = tid & 255, kc = tid >> 8;
            const f16x2* Wq2 = (const f16x2*)WqS;
            const float4* xb = (const float4*)(x2 + kc * 32);
            float a0=0.f, a1=0.f, a2=0.f, a3=0.f;
            #pragma unroll
            for (int u = 0; u < 8; ++u) {
                F4H8 xv; xv.f4 = xb[u];
                int k2 = kc * 32 + u * 4;
                a0 = __builtin_amdgcn_fdot2(Wq2[(k2+0)*256 + m], xv.h2[0], a0, false);
                a1 = __builtin_amdgcn_fdot2(Wq2[(k2+1)*256 + m], xv.h2[1], a1, false);
                a2 = __builtin_amdgcn_fdot2(Wq2[(k2+2)*256 + m], xv.h2[2], a2, false);
                a3 = __builtin_amdgcn_fdot2(Wq2[(k2+3)*256 + m], xv.h2[3], a3, false);
            }
            redA[kc * 256 + m] = (a0 + a1) + (a2 + a3);
        }
        { // A2: rz-hidden partials (streamed, 2-way k-split)
            int j = tid & 511, kq = tid >> 9;
            const uint2* wc = (const uint2*)WrzHH + (size_t)(kq * 32) * 512 + j;
            float a0=0.f,a1=0.f,a2=0.f,a3=0.f;
            #pragma unroll
            for (int i2 = 0; i2 < 32; i2 += 2) {
                U2H4 w0; w0.u2 = wc[(size_t)i2 * 512];
                U2H4 w1; w1.u2 = wc[(size_t)(i2 + 1) * 512];
                int k2 = kq * 64 + 2 * i2;
                F4H8 xv; xv.f4 = *(const float4*)&x2[k2];
                a0 = __builtin_amdgcn_fdot2(w0.h2[0], xv.h2[0], a0, false);
                a1 = __builtin_amdgcn_fdot2(w0.h2[1], xv.h2[1], a1, false);
                a2 = __builtin_amdgcn_fdot2(w1.h2[0], xv.h2[2], a2, false);
                a3 = __builtin_amdgcn_fdot2(w1.h2[1], xv.h2[3], a3, false);
            }
            redB[tid] = (a0 + a1) + (a2 + a3);
        }
        { // A3: n-hidden partials (streamed, 4-way k-split)
            int jn = tid & 255, sq = tid >> 8;
            const uint2* wn = (const uint2*)WnHH + (size_t)(sq * 16) * 256 + jn;
            float b0=0.f, b1=0.f;
            #pragma unroll
            for (int i2 = 0; i2 < 16; ++i2) {
                U2H4 w; w.u2 = wn[(size_t)i2 * 256];
                U2H4 xx; xx.u2 = *(const uint2*)&x2[sq * 32 + 2 * i2];
                b0 = __builtin_amdgcn_fdot2(w.h2[0], xx.h2[0], b0, false);
                b1 = __builtin_amdgcn_fdot2(w.h2[1], xx.h2[1], b1, false);
            }
            redC[sq * 256 + jn] = b0 + b1;
        }
        __syncthreads();
        if (tid < 256) { // B: tq = tanh(q); pack per-h constants
            float q = redA[tid] + redA[256 + tid] + redA[512 + tid] + redA[768 + tid];
            float tq = tanh_(q);
            float vv = vls[tid];
            float4 c = { tq, vv * tq, vv, 0.f };
            tqv[tid] = c;
        }
        __syncthreads();
        { // C: score partials: v*tanh(K+q) = (v*T + v*tq) / (1 + T*tq)
            int l = tid & 255, hg = tid >> 8;
            const __half* Tb = TH_b + (size_t)(hg * 64) * 256 + l;
            float s0=0.f,s1=0.f,s2=0.f,s3=0.f;
            #pragma unroll
            for (int i = 0; i < 64; i += 4) {
                float4 c0 = tqv[hg * 64 + i + 0];
                float T0 = __half2float(Tb[(size_t)(i + 0) * 256]);
                s0 = fmaf(fmaf(c0.z, T0, c0.y), rcp_(fmaf(T0, c0.x, 1.f)), s0);
                float4 c1 = tqv[hg * 64 + i + 1];
                float T1 = __half2float(Tb[(size_t)(i + 1) * 256]);
                s1 = fmaf(fmaf(c1.z, T1, c1.y), rcp_(fmaf(T1, c1.x, 1.f)), s1);
                float4 c2 = tqv[hg * 64 + i + 2];
                float T2 = __half2float(Tb[(size_t)(i + 2) * 256]);
                s2 = fmaf(fmaf(c2.z, T2, c2.y), rcp_(fmaf(T2, c2.x, 1.f)), s2);
                float4 c3 = tqv[hg * 64 + i + 3];
                float T3 = __half2float(Tb[(size_t)(i + 3) * 256]);
                s3 = fmaf(fmaf(c3.z, T3, c3.y), rcp_(fmaf(T3, c3.x, 1.f)), s3);
            }
            redA[hg * 256 + l] = (s0 + s1) + (s2 + s3);
        }
        __syncthreads();
        if (tid < 256) { // D: softmax numerator (|score| <= sum|v| ~ 8 -> no max pass)
            float sv = redA[tid] + redA[256 + tid] + redA[512 + tid] + redA[768 + tid];
            float e = __expf(sv);
            attn[tid] = e;
            float s = e;
            #pragma unroll
            for (int o = 1; o < 64; o <<= 1) s += __shfl_xor(s, o, 64);
            if ((tid & 63) == 0) wred[4 + (tid >> 6)] = s;
        }
        __syncthreads();
        { // E: ctx partials, 4-way l-split
            int ho = tid & 255, lc = tid >> 8;
            const __half* Ab = AOH_b + (size_t)(lc * 64) * 256 + ho;
            float c0=0.f,c1=0.f,c2=0.f,c3=0.f;
            #pragma unroll
            for (int i = 0; i < 64; i += 4) {
                c0 = fmaf(attn[lc * 64 + i + 0], __half2float(Ab[(size_t)(i + 0) * 256]), c0);
                c1 = fmaf(attn[lc * 64 + i + 1], __half2float(Ab[(size_t)(i + 1) * 256]), c1);
                c2 = fmaf(attn[lc * 64 + i + 2], __half2float(Ab[(size_t)(i + 2) * 256]), c2);
                c3 = fmaf(attn[lc * 64 + i + 3], __half2float(Ab[(size_t)(i + 3) * 256]), c3);
            }
            redD[lc * 256 + ho] = (c0 + c1) + (c2 + c3);
        }
        __syncthreads();
        if (tid < 256) { // F: finalize ctx -> x2[128+]
            float rs = rcp_(wred[4] + wred[5] + wred[6] + wred[7]);
            float cv = (redD[tid] + redD[256 + tid] + redD[512 + tid] + redD[768 + tid]) * rs;
            float other = __shfl_xor(cv, 1, 64);
            if (!(tid & 1)) {
                f16x2 v = { (_Float16)cv, (_Float16)other };
                x2[128 + (tid >> 1)] = v;
            }
        }
        __syncthreads();
        // G: gate-ctx partials (streamed)
        { // rz-ctx
            int j = tid & 511, kq = tid >> 9;
            const uint2* wc = (const uint2*)WrzCH + (size_t)(kq * 32) * 512 + j;
            float a0=0.f,a1=0.f,a2=0.f,a3=0.f;
            #pragma unroll
            for (int i2 = 0; i2 < 32; i2 += 2) {
                U2H4 w0; w0.u2 = wc[(size_t)i2 * 512];
                U2H4 w1; w1.u2 = wc[(size_t)(i2 + 1) * 512];
                int k2 = 128 + kq * 64 + 2 * i2;
                F4H8 xv; xv.f4 = *(const float4*)&x2[k2];
                a0 = __builtin_amdgcn_fdot2(w0.h2[0], xv.h2[0], a0, false);
                a1 = __builtin_amdgcn_fdot2(w0.h2[1], xv.h2[1], a1, false);
                a2 = __builtin_amdgcn_fdot2(w1.h2[0], xv.h2[2], a2, false);
                a3 = __builtin_amdgcn_fdot2(w1.h2[1], xv.h2[3], a3, false);
            }
            redA[tid] = (a0 + a1) + (a2 + a3);
        }
        { // n-ctx
            int jn = tid & 255, sq = tid >> 8;
            const uint2* wn = (const uint2*)WnCH + (size_t)(sq * 16) * 256 + jn;
            float b0=0.f, b1=0.f;
            #pragma unroll
            for (int i2 = 0; i2 < 16; ++i2) {
                U2H4 w; w.u2 = wn[(size_t)i2 * 256];
                U2H4 xx; xx.u2 = *(const uint2*)&x2[128 + sq * 32 + 2 * i2];
                b0 = __builtin_amdgcn_fdot2(w.h2[0], xx.h2[0], b0, false);
                b1 = __builtin_amdgcn_fdot2(w.h2[1], xx.h2[1], b1, false);
            }
            redD[sq * 256 + jn] = b0 + b1;
        }
        __syncthreads();
        if (tid < 256) { // H: gate reduce + GRU update
            const float* gi = GI + ((size_t)t * BB + b) * G3;
            float rr = (redB[tid] + redB[512 + tid]) + (redA[tid] + redA[512 + tid]);
            float zz = (redB[256 + tid] + redB[768 + tid]) + (redA[256 + tid] + redA[768 + tid]);
            float nh = (redC[tid] + redC[256 + tid]) + (redC[512 + tid] + redC[768 + tid]);
            float nc = (redD[tid] + redD[256 + tid]) + (redD[512 + tid] + redD[768 + tid]);
            float r = sigm(gi[tid] + rr + bhh[tid]);
            float z = sigm(gi[256 + tid] + zz + bhh[256 + tid]);
            float n = tanh_(gi[512 + tid] + nc + r * (nh + bhh[512 + tid]));
            float hk = hs[tid];
            float hn = (1.f - z) * n + z * hk;
            float hnew = (len < t) ? hk : hn;        // strict '<' per reference
            hs[tid] = hnew;
            if (t < len) csum += hnew;
            float other = __shfl_xor(hnew, 1, 64);
            if (!(tid & 1)) {
                f16x2 v = { (_Float16)hnew, (_Float16)other };
                x2[tid >> 1] = v;
            }
        }
        __syncthreads();
    }
    if (tid < 256) outp[8192 + b * HV + tid] = csum / (float)len;
}

extern "C" void kernel_launch(void* const* d_in, const int* in_sizes, int n_in,
                              void* d_out, int out_size, void* d_ws, size_t ws_size,
                              hipStream_t stream) {
    const int* anchor_input     = (const int*)d_in[0];
    const int* anchor_length    = (const int*)d_in[1];
    const int* candidate_input  = (const int*)d_in[2];
    const int* candidate_length = (const int*)d_in[3];
    const float* emb    = (const float*)d_in[5];
    const float* W_ih_a = (const float*)d_in[6];
    const float* W_hh_a = (const float*)d_in[7];
    const float* b_ih_a = (const float*)d_in[8];
    const float* b_hh_a = (const float*)d_in[9];
    const float* W_ih_c = (const float*)d_in[10];
    const float* W_hh_c = (const float*)d_in[11];
    const float* b_ih_c = (const float*)d_in[12];
    const float* b_hh_c = (const float*)d_in[13];
    const float* Wq     = (const float*)d_in[14];
    const float* Wk     = (const float*)d_in[15];
    const float* v_att  = (const float*)d_in[16];
    float* out = (float*)d_out;

    // workspace layout (float units), ~70.7 MB
    float* ws = (float*)d_ws;
    size_t off = 0;
    float* GI_a  = ws + off; off += (size_t)LAV * BB * G3;     // 6291456
    float* GI_c  = ws + off; off += (size_t)LCV * BB * G3;     // 6291456
    float* AO    = ws + off; off += (size_t)BB * LAV * HV;     // 2097152
    float* hid   = ws + off; off += (size_t)BB * HV;           // 8192
    float* WT_a  = ws + off; off += 300 * 768;                 // 230400
    float* WT_cx = ws + off; off += 300 * 768;                 // 230400
    float* Whha4 = ws + off; off += 64 * 768 * 4;              // 196608
    __half* TH    = (__half*)(ws + off); off += (size_t)BB * HV * LAV / 2;  // [b][h][l]
    __half* AOH   = (__half*)(ws + off); off += (size_t)BB * LAV * HV / 2;  // [b][l][h]
    __half* WqP   = (__half*)(ws + off); off += 65536 / 2;
    __half* WrzHH = (__half*)(ws + off); off += 131072 / 2;
    __half* WrzCH = (__half*)(ws + off); off += 131072 / 2;
    __half* WnHH  = (__half*)(ws + off); off += 65536 / 2;
    __half* WnCH  = (__half*)(ws + off); off += 65536 / 2;

    prep_pack<<<dim3(900, 8), 256, 0, stream>>>(W_ih_a, W_ih_c, W_hh_a, W_hh_c, Wq,
                                                WT_a, WT_cx, Whha4, WqP,
                                                WrzHH, WrzCH, WnHH, WnCH);
    gemm_tile<0><<<dim3(128, 12), 256, 0, stream>>>(emb, anchor_input, DV, WT_a, DV, G3, b_ih_a, GI_a);
    gemm_tile<0><<<dim3(128, 12), 256, 0, stream>>>(emb, candidate_input, DV, WT_cx, DV, G3, b_ih_c, GI_c);
    anchor_rnn<<<32, 384, 0, stream>>>(GI_a, anchor_length, b_hh_a, Whha4, AO, AOH, hid, out);
    gemm_tile<1><<<dim3(128, 4), 256, 0, stream>>>(AO, nullptr, HV, Wk, HV, HV, nullptr, (float*)TH);
    cand_rnn<<<32, 1024, 0, stream>>>(GI_c, candidate_length, b_hh_c, WrzHH, WrzCH,
                                      WnHH, WnCH, WqP, v_att, AOH, TH, hid, out);
}

// Round 8
// 4218.158 us; speedup vs baseline: 3.1150x; 3.1150x over previous
//
#include <hip/hip_runtime.h>
#include <hip/hip_fp16.h>
#include <math.h>

#define BB 32
#define LAV 256
#define LCV 256
#define DV 300
#define HV 256
#define G3 768   // 3*H

typedef _Float16 f16x2 __attribute__((ext_vector_type(2)));
union F4H8 { float4 f4; f16x2 h2[4]; };
union U2H4 { uint2 u2; f16x2 h2[2]; };

// ---------- fast math helpers ----------
static __device__ __forceinline__ float rcp_(float x) { return __builtin_amdgcn_rcpf(x); }
static __device__ __forceinline__ float sigm(float x) { return rcp_(1.f + __expf(-x)); }
static __device__ __forceinline__ float tanh_(float x) { return 1.f - 2.f * rcp_(1.f + __expf(2.f * x)); }

// ---------- weight packing ----------
// c0: WT_a  [300][768] = W_ih_a^T (fp32)
// c1: WT_cx [300][768] = W_ih_c[:,:300]^T (fp32)
// c2: WhaRH half anchor reg slice [768 t][64 ii][2 e]: W_hh_a[t][2*ii+e]
// c3: WhaSH half anchor stream    [32 i2][768 j][2 s][2 e]: k2=64+2*i2+s, W_hh_a[j][2*k2+e]
// c4: WqH   half [128 k2][256 m][2 e] = Wq[2*k2+e][m]
// c5: WrzH  half [256 kk][512 j][2 e]: kh=kk>>7,k2i=kk&127,k=kh*256+2*k2i+e;
//     W[k][j] = k<256 ? W_hh_c[j][k] : W_ih_c[j][300+(k-256)]     (r,z rows j<512)
// c6: WnH   half [256 gg][256 j][2 e]: slot=gg>>6,k2i=gg&63,grp=slot>>1,kh=slot&1,
//     kl=kh*128+2*k2i+e; grp0: W_hh_c[512+j][kl], grp1: W_ih_c[512+j][300+kl]  (n rows)
__global__ void prep_pack(const float* __restrict__ W_ih_a, const float* __restrict__ W_ih_c,
                          const float* __restrict__ W_hh_a, const float* __restrict__ W_hh_c,
                          const float* __restrict__ Wq,
                          float* __restrict__ WT_a, float* __restrict__ WT_cx,
                          __half* __restrict__ WhaRH, __half* __restrict__ WhaSH,
                          __half* __restrict__ WqH, __half* __restrict__ WrzH,
                          __half* __restrict__ WnH)
{
    int i = blockIdx.x * 256 + threadIdx.x;
    switch (blockIdx.y) {
    case 0: if (i < 230400) { int k = i / 768, n = i % 768; WT_a[i] = W_ih_a[n * 300 + k]; } break;
    case 1: if (i < 230400) { int k = i / 768, n = i % 768; WT_cx[i] = W_ih_c[n * 556 + k]; } break;
    case 2: if (i < 98304) { int e = i & 1, r = i >> 1, ii = r & 63, j = r >> 6;
            WhaRH[i] = __float2half(W_hh_a[j * 256 + 2 * ii + e]); } break;
    case 3: if (i < 98304) { int e = i & 1, s = (i >> 1) & 1, r = i >> 2, j = r % 768, i2 = r / 768;
            int k = 2 * (64 + 2 * i2 + s) + e;
            WhaSH[i] = __float2half(W_hh_a[j * 256 + k]); } break;
    case 4: if (i < 65536) { int e = i & 1, r2 = i >> 1, m = r2 & 255, k2 = r2 >> 8;
            WqH[i] = __float2half(Wq[(2 * k2 + e) * 256 + m]); } break;
    case 5: if (i < 262144) { int e = i & 1, r2 = i >> 1, j = r2 & 511, kk = r2 >> 9;
            int kh = kk >> 7, k2i = kk & 127, k = kh * 256 + 2 * k2i + e;
            float v = (k < 256) ? W_hh_c[j * 256 + k] : W_ih_c[j * 556 + 300 + (k - 256)];
            WrzH[i] = __float2half(v); } break;
    case 6: if (i < 131072) { int e = i & 1, r2 = i >> 1, j = r2 & 255, gg = r2 >> 8;
            int slot = gg >> 6, k2i = gg & 63, grp = slot >> 1, kh = slot & 1;
            int kl = kh * 128 + 2 * k2i + e;
            float v = grp ? W_ih_c[(512 + j) * 556 + 300 + kl] : W_hh_c[(512 + j) * 256 + kl];
            WnH[i] = __float2half(v); } break;
    }
}

// ---------- tiled fp32 GEMM ----------
// MODE 0: Cout[m*N+n] = acc + bias[n]                       (GI precompute)
// MODE 1: TH half2[b][h][l2] = {tanh(acc@l), tanh(acc@l+1)} (keys -> T)
template <int MODE>
__global__ __launch_bounds__(256) void gemm_tile(
    const float* __restrict__ X, const int* __restrict__ gidx, int ldx,
    const float* __restrict__ Wt, int K, int Nn,
    const float* __restrict__ bias, float* __restrict__ Cout)
{
    __shared__ __align__(16) float As[32][68];
    __shared__ __align__(16) float Bs[32][68];
    __shared__ int toks[64];
    int tid = threadIdx.x;
    int m0 = blockIdx.x * 64, n0 = blockIdx.y * 64;
    if (tid < 64) {
        int m = m0 + tid;
        if (gidx) { int t = m >> 5, b = m & 31; toks[tid] = gidx[b * LAV + t]; }
        else toks[tid] = m;
    }
    __syncthreads();
    float acc[4][4] = {};
    int tx = tid & 15, ty = tid >> 4;
    for (int k0 = 0; k0 < K; k0 += 32) {
        {
            int r = tid >> 2, cc = (tid & 3) * 8;
            const float* src = X + (size_t)toks[r] * ldx + k0 + cc;
            float4 v0 = {0.f,0.f,0.f,0.f}, v1 = {0.f,0.f,0.f,0.f};
            if (k0 + cc + 3 < K) v0 = *(const float4*)src;
            if (k0 + cc + 7 < K) v1 = *(const float4*)(src + 4);
            As[cc+0][r]=v0.x; As[cc+1][r]=v0.y; As[cc+2][r]=v0.z; As[cc+3][r]=v0.w;
            As[cc+4][r]=v1.x; As[cc+5][r]=v1.y; As[cc+6][r]=v1.z; As[cc+7][r]=v1.w;
        }
        {
            int kr = tid >> 4, c4 = (tid & 15) * 4;
            #pragma unroll
            for (int p = 0; p < 2; ++p) {
                float4 v = {0.f,0.f,0.f,0.f};
                int kg = k0 + kr + p * 16;
                if (kg < K) v = *(const float4*)(Wt + (size_t)kg * Nn + n0 + c4);
                *(float4*)&Bs[kr + p * 16][c4] = v;
            }
        }
        __syncthreads();
        #pragma unroll 8
        for (int kk = 0; kk < 32; ++kk) {
            float4 a4 = *(const float4*)&As[kk][ty * 4];
            float4 b4 = *(const float4*)&Bs[kk][tx * 4];
            acc[0][0]=fmaf(a4.x,b4.x,acc[0][0]); acc[0][1]=fmaf(a4.x,b4.y,acc[0][1]);
            acc[0][2]=fmaf(a4.x,b4.z,acc[0][2]); acc[0][3]=fmaf(a4.x,b4.w,acc[0][3]);
            acc[1][0]=fmaf(a4.y,b4.x,acc[1][0]); acc[1][1]=fmaf(a4.y,b4.y,acc[1][1]);
            acc[1][2]=fmaf(a4.y,b4.z,acc[1][2]); acc[1][3]=fmaf(a4.y,b4.w,acc[1][3]);
            acc[2][0]=fmaf(a4.z,b4.x,acc[2][0]); acc[2][1]=fmaf(a4.z,b4.y,acc[2][1]);
            acc[2][2]=fmaf(a4.z,b4.z,acc[2][2]); acc[2][3]=fmaf(a4.z,b4.w,acc[2][3]);
            acc[3][0]=fmaf(a4.w,b4.x,acc[3][0]); acc[3][1]=fmaf(a4.w,b4.y,acc[3][1]);
            acc[3][2]=fmaf(a4.w,b4.z,acc[3][2]); acc[3][3]=fmaf(a4.w,b4.w,acc[3][3]);
        }
        __syncthreads();
    }
    if (MODE == 0) {
        float4 bz = *(const float4*)&bias[n0 + tx * 4];
        #pragma unroll
        for (int i = 0; i < 4; ++i) {
            int m = m0 + ty * 4 + i;
            float4 o = { acc[i][0] + bz.x, acc[i][1] + bz.y, acc[i][2] + bz.z, acc[i][3] + bz.w };
            *(float4*)&Cout[(size_t)m * Nn + n0 + tx * 4] = o;
        }
    } else {
        int b_ = m0 >> 8;
        int l0 = (m0 & 255) + ty * 4;
        f16x2* TH = (f16x2*)Cout;
        #pragma unroll
        for (int j = 0; j < 4; ++j) {
            int h = n0 + tx * 4 + j;
            size_t base = ((size_t)(b_ * 256 + h)) * 128 + (l0 >> 1);
            f16x2 v01 = { (_Float16)tanh_(acc[0][j]), (_Float16)tanh_(acc[1][j]) };
            f16x2 v23 = { (_Float16)tanh_(acc[2][j]), (_Float16)tanh_(acc[3][j]) };
            TH[base] = v01;
            TH[base + 1] = v23;
        }
    }
}

// ---------- anchor GRU: one WG/batch, fp16 (reg slice + stream) — R5-proven ----------
__global__ __launch_bounds__(768) void anchor_rnn(
    const float* __restrict__ GI, const int* __restrict__ lens,
    const float* __restrict__ bhh, const __half* __restrict__ WhaRH,
    const __half* __restrict__ WhaSH,
    float* __restrict__ AO, __half* __restrict__ AOH,
    float* __restrict__ hid, float* __restrict__ outp)
{
    __shared__ float gh[768];
    __shared__ __align__(16) float hs[256];
    __shared__ __align__(16) f16x2 hx2[128];
    __shared__ float bhhS[768];
    int bid = blockIdx.x, tid = threadIdx.x;
    int len = lens[bid];

    f16x2 wreg[64];
    {
        const float4* s = (const float4*)WhaRH + (size_t)tid * 16;
        #pragma unroll
        for (int u = 0; u < 16; ++u) {
            F4H8 c; c.f4 = s[u];
            wreg[4*u+0] = c.h2[0]; wreg[4*u+1] = c.h2[1];
            wreg[4*u+2] = c.h2[2]; wreg[4*u+3] = c.h2[3];
        }
    }
    if (tid < 256) hs[tid] = 0.f;
    if (tid < 128) { f16x2 z = {(_Float16)0.f, (_Float16)0.f}; hx2[tid] = z; }
    bhhS[tid] = bhh[tid];
    float sum = 0.f;
    __syncthreads();

    for (int t = 0; t < LAV; ++t) {
        { // gh[j] = W_hh_a[j,:] @ h (+ b_hh): k2 0..63 from regs + k2 64..127 streamed
            float a0=0.f,a1=0.f,a2=0.f,a3=0.f;
            const float4* xb = (const float4*)hx2;
            #pragma unroll
            for (int u = 0; u < 16; ++u) {
                F4H8 xv; xv.f4 = xb[u];
                a0 = __builtin_amdgcn_fdot2(wreg[4*u+0], xv.h2[0], a0, false);
                a1 = __builtin_amdgcn_fdot2(wreg[4*u+1], xv.h2[1], a1, false);
                a2 = __builtin_amdgcn_fdot2(wreg[4*u+2], xv.h2[2], a2, false);
                a3 = __builtin_amdgcn_fdot2(wreg[4*u+3], xv.h2[3], a3, false);
            }
            const uint2* wsp = (const uint2*)WhaSH + tid;
            float b0=0.f,b1=0.f;
            #pragma unroll
            for (int i2 = 0; i2 < 32; ++i2) {   // full 32 i2 slots (k2 64..127)
                U2H4 w; w.u2 = wsp[(size_t)i2 * 768];
                U2H4 xx; xx.u2 = *(const uint2*)&hx2[64 + 2 * i2];
                b0 = __builtin_amdgcn_fdot2(w.h2[0], xx.h2[0], b0, false);
                b1 = __builtin_amdgcn_fdot2(w.h2[1], xx.h2[1], b1, false);
            }
            gh[tid] = ((a0 + a1) + (a2 + a3)) + (b0 + b1) + bhhS[tid];
        }
        __syncthreads();
        if (tid < 256) {
            const float* gi = GI + ((size_t)t * BB + bid) * G3;
            float r = sigm(gi[tid] + gh[tid]);
            float z = sigm(gi[256 + tid] + gh[256 + tid]);
            float n = tanh_(fmaf(r, gh[512 + tid], gi[512 + tid]));
            float hk = hs[tid];
            float hn = (1.f - z) * n + z * hk;
            bool valid = (t < len);
            float hnew = valid ? hn : hk;
            hs[tid] = hnew;
            float ov = valid ? hn : 0.f;
            AO[((size_t)bid * LAV + t) * HV + tid] = ov;
            AOH[((size_t)bid * LAV + t) * HV + tid] = __float2half(ov);
            sum += ov;
            float other = __shfl_xor(hnew, 1, 64);
            if (!(tid & 1)) {
                f16x2 v = { (_Float16)hnew, (_Float16)other };
                hx2[tid >> 1] = v;
            }
        }
        __syncthreads();
    }
    if (tid < 256) {
        outp[bid * HV + tid] = sum / (float)len;
        hid[bid * HV + tid] = hs[tid];
    }
}

// ---------- candidate GRU + attention: one WG per batch, fp16 weights, fdot2 — R3-proven ----------
__global__ __launch_bounds__(1024) void cand_rnn(
    const float* __restrict__ GI, const int* __restrict__ lens,
    const float* __restrict__ bhh, const __half* __restrict__ WrzH,
    const __half* __restrict__ WnH, const __half* __restrict__ WqH,
    const float* __restrict__ v_att, const __half* __restrict__ AOH,
    const __half* __restrict__ TH, const float* __restrict__ hid,
    float* __restrict__ outp)
{
    __shared__ __align__(16) f16x2 x2[256];   // [h pairs(128); ctx pairs(128)]
    __shared__ __align__(16) float hs[256];
    __shared__ float tqs[256];
    __shared__ float vls[256];
    __shared__ float attn[256];
    __shared__ __align__(16) float red[3072];
    __shared__ float bhhS[768];
    __shared__ float wred[8];

    int tid = threadIdx.x;
    int b = blockIdx.x;
    int len = lens[b];

    const f16x2* Wq2  = (const f16x2*)WqH;
    const f16x2* Wrz2 = (const f16x2*)WrzH;
    const f16x2* Wn2  = (const f16x2*)WnH;
    const f16x2* T2   = (const f16x2*)TH + (size_t)b * 256 * 128;
    const f16x2* AO2  = (const f16x2*)AOH + (size_t)b * 256 * 128;

    if (tid < 256) { hs[tid] = hid[b * HV + tid]; vls[tid] = v_att[tid]; }
    if (tid < 768) bhhS[tid] = bhh[tid];
    __syncthreads();
    if (tid < 128) {
        f16x2 v = { (_Float16)hs[2 * tid], (_Float16)hs[2 * tid + 1] };
        x2[tid] = v;
    }
    __syncthreads();

    float csum = 0.f;

    for (int t = 0; t < LCV; ++t) {
        { // P0: q partials, 4-way k-split: q[m] = sum_k h[k] Wq[k][m]
            int m = tid & 255, kc = tid >> 8;
            float a0 = 0.f, a1 = 0.f;
            #pragma unroll 8
            for (int i = 0; i < 32; i += 2) {
                int k2 = kc * 32 + i;
                a0 = __builtin_amdgcn_fdot2(Wq2[k2 * 256 + m], x2[k2], a0, false);
                a1 = __builtin_amdgcn_fdot2(Wq2[(k2 + 1) * 256 + m], x2[k2 + 1], a1, false);
            }
            red[kc * 256 + m] = a0 + a1;
        }
        __syncthreads();
        if (tid < 256) { // P0b: tq = tanh(q)
            float q = red[tid] + red[256 + tid] + red[512 + tid] + red[768 + tid];
            tqs[tid] = tanh_(q);
        }
        __syncthreads();
        { // P1: score partials: tanh(k+q) = (T+tq)/(1+T*tq)
            int l2 = tid & 127, hg = tid >> 7;
            float s0 = 0.f, s1 = 0.f;
            #pragma unroll 8
            for (int i = 0; i < 32; ++i) {
                int h = hg * 32 + i;
                f16x2 Tv = T2[(size_t)h * 128 + l2];
                float tq = tqs[h], vv = vls[h];
                float T0 = (float)Tv.x, T1 = (float)Tv.y;
                float d0 = fmaxf(fmaf(T0, tq, 1.f), 1e-6f);
                float d1 = fmaxf(fmaf(T1, tq, 1.f), 1e-6f);
                s0 = fmaf(vv * (T0 + tq), rcp_(d0), s0);
                s1 = fmaf(vv * (T1 + tq), rcp_(d1), s1);
            }
            red[hg * 256 + 2 * l2] = s0;
            red[hg * 256 + 2 * l2 + 1] = s1;
        }
        __syncthreads();
        float sv = 0.f;
        if (tid < 256) { // P2a: reduce 8 partials + wave max
            #pragma unroll
            for (int hg = 0; hg < 8; ++hg) sv += red[hg * 256 + tid];
            float m = sv;
            #pragma unroll
            for (int o = 1; o < 64; o <<= 1) m = fmaxf(m, __shfl_xor(m, o, 64));
            if ((tid & 63) == 0) wred[tid >> 6] = m;
        }
        __syncthreads();
        if (tid < 256) { // P2b: exp + wave sum
            float mx = fmaxf(fmaxf(wred[0], wred[1]), fmaxf(wred[2], wred[3]));
            float e = __expf(sv - mx);
            attn[tid] = e;
            float s = e;
            #pragma unroll
            for (int o = 1; o < 64; o <<= 1) s += __shfl_xor(s, o, 64);
            if ((tid & 63) == 0) wred[4 + (tid >> 6)] = s;
        }
        __syncthreads();
        { // P3: ctx partials, 8-way l-split
            int ho2 = tid & 127, lc = tid >> 7;
            float c0 = 0.f, c1 = 0.f;
            #pragma unroll 8
            for (int i = 0; i < 32; ++i) {
                int l = lc * 32 + i;
                f16x2 ao = AO2[(size_t)l * 128 + ho2];
                float w = attn[l];
                c0 = fmaf(w, (float)ao.x, c0);
                c1 = fmaf(w, (float)ao.y, c1);
            }
            red[lc * 256 + 2 * ho2] = c0;
            red[lc * 256 + 2 * ho2 + 1] = c1;
        }
        __syncthreads();
        if (tid < 128) { // P3b: finalize ctx pair -> x2[128+]
            float c0 = 0.f, c1 = 0.f;
            #pragma unroll
            for (int lc = 0; lc < 8; ++lc) {
                c0 += red[lc * 256 + 2 * tid];
                c1 += red[lc * 256 + 2 * tid + 1];
            }
            float rs = rcp_(wred[4] + wred[5] + wred[6] + wred[7]);
            f16x2 v = { (_Float16)(c0 * rs), (_Float16)(c1 * rs) };
            x2[128 + tid] = v;
        }
        __syncthreads();
        { // P4A: r,z gates, 2-way k-split: 1024 tasks x 128 fdot2
            int j = tid & 511, kh = tid >> 9;
            float a0 = 0.f, a1 = 0.f;
            #pragma unroll 8
            for (int i = 0; i < 128; i += 2) {
                int kk = kh * 128 + i;
                a0 = __builtin_amdgcn_fdot2(Wrz2[(size_t)kk * 512 + j], x2[kk], a0, false);
                a1 = __builtin_amdgcn_fdot2(Wrz2[(size_t)(kk + 1) * 512 + j], x2[kk + 1], a1, false);
            }
            red[tid] = a0 + a1;
        }
        { // P4B: n gates (hidden / ctx), 2-way k-split: 1024 tasks x 64 fdot2
            int j = tid & 255, slot = tid >> 8;       // slot = (grp<<1)|kh
            int grp = slot >> 1, kh = slot & 1;
            int xb = grp * 128 + kh * 64;
            float a0 = 0.f, a1 = 0.f;
            #pragma unroll 8
            for (int i = 0; i < 64; i += 2) {
                int gg = slot * 64 + i;
                a0 = __builtin_amdgcn_fdot2(Wn2[(size_t)gg * 256 + j], x2[xb + i], a0, false);
                a1 = __builtin_amdgcn_fdot2(Wn2[(size_t)(gg + 1) * 256 + j], x2[xb + i + 1], a1, false);
            }
            red[1024 + tid] = a0 + a1;
        }
        __syncthreads();
        if (tid < 256) { // P5: gate reduce + GRU update
            const float* gi = GI + ((size_t)t * BB + b) * G3;
            float rr = red[tid] + red[512 + tid];
            float zz = red[256 + tid] + red[768 + tid];
            float nh = red[1024 + tid] + red[1280 + tid];
            float nc = red[1536 + tid] + red[1792 + tid];
            float r = sigm(gi[tid] + rr + bhhS[tid]);
            float z = sigm(gi[256 + tid] + zz + bhhS[256 + tid]);
            float n = tanh_(gi[512 + tid] + nc + r * (nh + bhhS[512 + tid]));
            float hk = hs[tid];
            float hn = (1.f - z) * n + z * hk;
            float hnew = (len < t) ? hk : hn;        // strict '<' per reference
            hs[tid] = hnew;
            if (t < len) csum += hnew;
            // rebuild h half2 pairs via shfl (lane pairs within a wave)
            float other = __shfl_xor(hnew, 1, 64);
            if ((tid & 1) == 0) {
                f16x2 v = { (_Float16)hnew, (_Float16)other };
                x2[tid >> 1] = v;
            }
        }
        __syncthreads();
    }
    if (tid < 256) outp[8192 + b * HV + tid] = csum / (float)len;
}

extern "C" void kernel_launch(void* const* d_in, const int* in_sizes, int n_in,
                              void* d_out, int out_size, void* d_ws, size_t ws_size,
                              hipStream_t stream) {
    const int* anchor_input     = (const int*)d_in[0];
    const int* anchor_length    = (const int*)d_in[1];
    const int* candidate_input  = (const int*)d_in[2];
    const int* candidate_length = (const int*)d_in[3];
    const float* emb    = (const float*)d_in[5];
    const float* W_ih_a = (const float*)d_in[6];
    const float* W_hh_a = (const float*)d_in[7];
    const float* b_ih_a = (const float*)d_in[8];
    const float* b_hh_a = (const float*)d_in[9];
    const float* W_ih_c = (const float*)d_in[10];
    const float* W_hh_c = (const float*)d_in[11];
    const float* b_ih_c = (const float*)d_in[12];
    const float* b_hh_c = (const float*)d_in[13];
    const float* Wq     = (const float*)d_in[14];
    const float* Wk     = (const float*)d_in[15];
    const float* v_att  = (const float*)d_in[16];
    float* out = (float*)d_out;

    // workspace layout (float units), ~70.7 MB
    float* ws = (float*)d_ws;
    size_t off = 0;
    float* GI_a  = ws + off; off += (size_t)LAV * BB * G3;     // 6291456
    float* GI_c  = ws + off; off += (size_t)LCV * BB * G3;     // 6291456
    float* AO    = ws + off; off += (size_t)BB * LAV * HV;     // 2097152
    float* hid   = ws + off; off += (size_t)BB * HV;           // 8192
    float* WT_a  = ws + off; off += 300 * 768;                 // 230400
    float* WT_cx = ws + off; off += 300 * 768;                 // 230400
    __half* TH    = (__half*)(ws + off); off += (size_t)BB * HV * LAV / 2;  // [b][h][l2] pairs
    __half* AOH   = (__half*)(ws + off); off += (size_t)BB * LAV * HV / 2;  // [b][l][h] pairs
    __half* WhaRH = (__half*)(ws + off); off += 98304 / 2;
    __half* WhaSH = (__half*)(ws + off); off += 98304 / 2;
    __half* WqH   = (__half*)(ws + off); off += 65536 / 2;
    __half* WrzH  = (__half*)(ws + off); off += 262144 / 2;
    __half* WnH   = (__half*)(ws + off); off += 131072 / 2;

    prep_pack<<<dim3(1024, 7), 256, 0, stream>>>(W_ih_a, W_ih_c, W_hh_a, W_hh_c, Wq,
                                                 WT_a, WT_cx, WhaRH, WhaSH, WqH, WrzH, WnH);
    gemm_tile<0><<<dim3(128, 12), 256, 0, stream>>>(emb, anchor_input, DV, WT_a, DV, G3, b_ih_a, GI_a);
    gemm_tile<0><<<dim3(128, 12), 256, 0, stream>>>(emb, candidate_input, DV, WT_cx, DV, G3, b_ih_c, GI_c);
    anchor_rnn<<<32, 768, 0, stream>>>(GI_a, anchor_length, b_hh_a, WhaRH, WhaSH, AO, AOH, hid, out);
    gemm_tile<1><<<dim3(128, 4), 256, 0, stream>>>(AO, nullptr, HV, Wk, HV, HV, nullptr, (float*)TH);
    cand_rnn<<<32, 1024, 0, stream>>>(GI_c, candidate_length, b_hh_c, WrzH, WnH, WqH,
                                      v_att, AOH, TH, hid, out);
}

// Round 9
// 3837.030 us; speedup vs baseline: 3.4244x; 1.0993x over previous
//
#include <hip/hip_runtime.h>
#include <hip/hip_fp16.h>
#include <math.h>

#define BB 32
#define LAV 256
#define LCV 256
#define DV 300
#define HV 256
#define G3 768   // 3*H

typedef _Float16 f16x2 __attribute__((ext_vector_type(2)));
union F4H8 { float4 f4; f16x2 h2[4]; };
union U2H4 { uint2 u2; f16x2 h2[2]; };

// ---------- fast math helpers ----------
static __device__ __forceinline__ float rcp_(float x) { return __builtin_amdgcn_rcpf(x); }
static __device__ __forceinline__ float sigm(float x) { return rcp_(1.f + __expf(-x)); }
static __device__ __forceinline__ float tanh_(float x) { return 1.f - 2.f * rcp_(1.f + __expf(2.f * x)); }

// ---------- weight packing ----------
// c0: WT_a  [300][768] = W_ih_a^T (fp32)
// c1: WT_cx [300][768] = W_ih_c[:,:300]^T (fp32)
// c2: WhaRH half anchor reg slice [768 t][64 ii][2 e]: W_hh_a[t][2*ii+e]
// c3: WhaSH half anchor stream    [32 i2][768 j][2 s][2 e]: k2=64+2*i2+s, W_hh_a[j][2*k2+e]
// c4: WqH   half [128 k2][256 m][2 e] = Wq[2*k2+e][m]
// c5: WrzH  half [256 kk][512 j][2 e]: kh=kk>>7,k2i=kk&127,k=kh*256+2*k2i+e;
//     W[k][j] = k<256 ? W_hh_c[j][k] : W_ih_c[j][300+(k-256)]     (r,z rows j<512)
// c6: WnH   half [256 gg][256 j][2 e]: slot=gg>>6,k2i=gg&63,grp=slot>>1,kh=slot&1,
//     kl=kh*128+2*k2i+e; grp0: W_hh_c[512+j][kl], grp1: W_ih_c[512+j][300+kl]  (n rows)
__global__ void prep_pack(const float* __restrict__ W_ih_a, const float* __restrict__ W_ih_c,
                          const float* __restrict__ W_hh_a, const float* __restrict__ W_hh_c,
                          const float* __restrict__ Wq,
                          float* __restrict__ WT_a, float* __restrict__ WT_cx,
                          __half* __restrict__ WhaRH, __half* __restrict__ WhaSH,
                          __half* __restrict__ WqH, __half* __restrict__ WrzH,
                          __half* __restrict__ WnH)
{
    int i = blockIdx.x * 256 + threadIdx.x;
    switch (blockIdx.y) {
    case 0: if (i < 230400) { int k = i / 768, n = i % 768; WT_a[i] = W_ih_a[n * 300 + k]; } break;
    case 1: if (i < 230400) { int k = i / 768, n = i % 768; WT_cx[i] = W_ih_c[n * 556 + k]; } break;
    case 2: if (i < 98304) { int e = i & 1, r = i >> 1, ii = r & 63, j = r >> 6;
            WhaRH[i] = __float2half(W_hh_a[j * 256 + 2 * ii + e]); } break;
    case 3: if (i < 98304) { int e = i & 1, s = (i >> 1) & 1, r = i >> 2, j = r % 768, i2 = r / 768;
            int k = 2 * (64 + 2 * i2 + s) + e;
            WhaSH[i] = __float2half(W_hh_a[j * 256 + k]); } break;
    case 4: if (i < 65536) { int e = i & 1, r2 = i >> 1, m = r2 & 255, k2 = r2 >> 8;
            WqH[i] = __float2half(Wq[(2 * k2 + e) * 256 + m]); } break;
    case 5: if (i < 262144) { int e = i & 1, r2 = i >> 1, j = r2 & 511, kk = r2 >> 9;
            int kh = kk >> 7, k2i = kk & 127, k = kh * 256 + 2 * k2i + e;
            float v = (k < 256) ? W_hh_c[j * 256 + k] : W_ih_c[j * 556 + 300 + (k - 256)];
            WrzH[i] = __float2half(v); } break;
    case 6: if (i < 131072) { int e = i & 1, r2 = i >> 1, j = r2 & 255, gg = r2 >> 8;
            int slot = gg >> 6, k2i = gg & 63, grp = slot >> 1, kh = slot & 1;
            int kl = kh * 128 + 2 * k2i + e;
            float v = grp ? W_ih_c[(512 + j) * 556 + 300 + kl] : W_hh_c[(512 + j) * 256 + kl];
            WnH[i] = __float2half(v); } break;
    }
}

// ---------- tiled fp32 GEMM ----------
// MODE 0: Cout[m*N+n] = acc + bias[n]                       (GI precompute)
// MODE 1: TH half2[b][h][l2] = {tanh(acc@l), tanh(acc@l+1)} (keys -> T)
template <int MODE>
__global__ __launch_bounds__(256) void gemm_tile(
    const float* __restrict__ X, const int* __restrict__ gidx, int ldx,
    const float* __restrict__ Wt, int K, int Nn,
    const float* __restrict__ bias, float* __restrict__ Cout)
{
    __shared__ __align__(16) float As[32][68];
    __shared__ __align__(16) float Bs[32][68];
    __shared__ int toks[64];
    int tid = threadIdx.x;
    int m0 = blockIdx.x * 64, n0 = blockIdx.y * 64;
    if (tid < 64) {
        int m = m0 + tid;
        if (gidx) { int t = m >> 5, b = m & 31; toks[tid] = gidx[b * LAV + t]; }
        else toks[tid] = m;
    }
    __syncthreads();
    float acc[4][4] = {};
    int tx = tid & 15, ty = tid >> 4;
    for (int k0 = 0; k0 < K; k0 += 32) {
        {
            int r = tid >> 2, cc = (tid & 3) * 8;
            const float* src = X + (size_t)toks[r] * ldx + k0 + cc;
            float4 v0 = {0.f,0.f,0.f,0.f}, v1 = {0.f,0.f,0.f,0.f};
            if (k0 + cc + 3 < K) v0 = *(const float4*)src;
            if (k0 + cc + 7 < K) v1 = *(const float4*)(src + 4);
            As[cc+0][r]=v0.x; As[cc+1][r]=v0.y; As[cc+2][r]=v0.z; As[cc+3][r]=v0.w;
            As[cc+4][r]=v1.x; As[cc+5][r]=v1.y; As[cc+6][r]=v1.z; As[cc+7][r]=v1.w;
        }
        {
            int kr = tid >> 4, c4 = (tid & 15) * 4;
            #pragma unroll
            for (int p = 0; p < 2; ++p) {
                float4 v = {0.f,0.f,0.f,0.f};
                int kg = k0 + kr + p * 16;
                if (kg < K) v = *(const float4*)(Wt + (size_t)kg * Nn + n0 + c4);
                *(float4*)&Bs[kr + p * 16][c4] = v;
            }
        }
        __syncthreads();
        #pragma unroll 8
        for (int kk = 0; kk < 32; ++kk) {
            float4 a4 = *(const float4*)&As[kk][ty * 4];
            float4 b4 = *(const float4*)&Bs[kk][tx * 4];
            acc[0][0]=fmaf(a4.x,b4.x,acc[0][0]); acc[0][1]=fmaf(a4.x,b4.y,acc[0][1]);
            acc[0][2]=fmaf(a4.x,b4.z,acc[0][2]); acc[0][3]=fmaf(a4.x,b4.w,acc[0][3]);
            acc[1][0]=fmaf(a4.y,b4.x,acc[1][0]); acc[1][1]=fmaf(a4.y,b4.y,acc[1][1]);
            acc[1][2]=fmaf(a4.y,b4.z,acc[1][2]); acc[1][3]=fmaf(a4.y,b4.w,acc[1][3]);
            acc[2][0]=fmaf(a4.z,b4.x,acc[2][0]); acc[2][1]=fmaf(a4.z,b4.y,acc[2][1]);
            acc[2][2]=fmaf(a4.z,b4.z,acc[2][2]); acc[2][3]=fmaf(a4.z,b4.w,acc[2][3]);
            acc[3][0]=fmaf(a4.w,b4.x,acc[3][0]); acc[3][1]=fmaf(a4.w,b4.y,acc[3][1]);
            acc[3][2]=fmaf(a4.w,b4.z,acc[3][2]); acc[3][3]=fmaf(a4.w,b4.w,acc[3][3]);
        }
        __syncthreads();
    }
    if (MODE == 0) {
        float4 bz = *(const float4*)&bias[n0 + tx * 4];
        #pragma unroll
        for (int i = 0; i < 4; ++i) {
            int m = m0 + ty * 4 + i;
            float4 o = { acc[i][0] + bz.x, acc[i][1] + bz.y, acc[i][2] + bz.z, acc[i][3] + bz.w };
            *(float4*)&Cout[(size_t)m * Nn + n0 + tx * 4] = o;
        }
    } else {
        int b_ = m0 >> 8;
        int l0 = (m0 & 255) + ty * 4;
        f16x2* TH = (f16x2*)Cout;
        #pragma unroll
        for (int j = 0; j < 4; ++j) {
            int h = n0 + tx * 4 + j;
            size_t base = ((size_t)(b_ * 256 + h)) * 128 + (l0 >> 1);
            f16x2 v01 = { (_Float16)tanh_(acc[0][j]), (_Float16)tanh_(acc[1][j]) };
            f16x2 v23 = { (_Float16)tanh_(acc[2][j]), (_Float16)tanh_(acc[3][j]) };
            TH[base] = v01;
            TH[base + 1] = v23;
        }
    }
}

// ---------- anchor GRU: one WG/batch, fp16 (reg slice + stream) — R5/R8-proven ----------
__global__ __launch_bounds__(768) void anchor_rnn(
    const float* __restrict__ GI, const int* __restrict__ lens,
    const float* __restrict__ bhh, const __half* __restrict__ WhaRH,
    const __half* __restrict__ WhaSH,
    float* __restrict__ AO, __half* __restrict__ AOH,
    float* __restrict__ hid, float* __restrict__ outp)
{
    __shared__ float gh[768];
    __shared__ __align__(16) float hs[256];
    __shared__ __align__(16) f16x2 hx2[128];
    __shared__ float bhhS[768];
    int bid = blockIdx.x, tid = threadIdx.x;
    int len = lens[bid];

    f16x2 wreg[64];
    {
        const float4* s = (const float4*)WhaRH + (size_t)tid * 16;
        #pragma unroll
        for (int u = 0; u < 16; ++u) {
            F4H8 c; c.f4 = s[u];
            wreg[4*u+0] = c.h2[0]; wreg[4*u+1] = c.h2[1];
            wreg[4*u+2] = c.h2[2]; wreg[4*u+3] = c.h2[3];
        }
    }
    if (tid < 256) hs[tid] = 0.f;
    if (tid < 128) { f16x2 z = {(_Float16)0.f, (_Float16)0.f}; hx2[tid] = z; }
    bhhS[tid] = bhh[tid];
    float sum = 0.f;
    __syncthreads();

    for (int t = 0; t < LAV; ++t) {
        { // gh[j] = W_hh_a[j,:] @ h (+ b_hh): k2 0..63 from regs + k2 64..127 streamed
            float a0=0.f,a1=0.f,a2=0.f,a3=0.f;
            const float4* xb = (const float4*)hx2;
            #pragma unroll
            for (int u = 0; u < 16; ++u) {
                F4H8 xv; xv.f4 = xb[u];
                a0 = __builtin_amdgcn_fdot2(wreg[4*u+0], xv.h2[0], a0, false);
                a1 = __builtin_amdgcn_fdot2(wreg[4*u+1], xv.h2[1], a1, false);
                a2 = __builtin_amdgcn_fdot2(wreg[4*u+2], xv.h2[2], a2, false);
                a3 = __builtin_amdgcn_fdot2(wreg[4*u+3], xv.h2[3], a3, false);
            }
            const uint2* wsp = (const uint2*)WhaSH + tid;
            float b0=0.f,b1=0.f;
            #pragma unroll
            for (int i2 = 0; i2 < 32; ++i2) {   // full 32 i2 slots (k2 64..127)
                U2H4 w; w.u2 = wsp[(size_t)i2 * 768];
                U2H4 xx; xx.u2 = *(const uint2*)&hx2[64 + 2 * i2];
                b0 = __builtin_amdgcn_fdot2(w.h2[0], xx.h2[0], b0, false);
                b1 = __builtin_amdgcn_fdot2(w.h2[1], xx.h2[1], b1, false);
            }
            gh[tid] = ((a0 + a1) + (a2 + a3)) + (b0 + b1) + bhhS[tid];
        }
        __syncthreads();
        if (tid < 256) {
            const float* gi = GI + ((size_t)t * BB + bid) * G3;
            float r = sigm(gi[tid] + gh[tid]);
            float z = sigm(gi[256 + tid] + gh[256 + tid]);
            float n = tanh_(fmaf(r, gh[512 + tid], gi[512 + tid]));
            float hk = hs[tid];
            float hn = (1.f - z) * n + z * hk;
            bool valid = (t < len);
            float hnew = valid ? hn : hk;
            hs[tid] = hnew;
            float ov = valid ? hn : 0.f;
            AO[((size_t)bid * LAV + t) * HV + tid] = ov;
            AOH[((size_t)bid * LAV + t) * HV + tid] = __float2half(ov);
            sum += ov;
            float other = __shfl_xor(hnew, 1, 64);
            if (!(tid & 1)) {
                f16x2 v = { (_Float16)hnew, (_Float16)other };
                hx2[tid >> 1] = v;
            }
        }
        __syncthreads();
    }
    if (tid < 256) {
        outp[bid * HV + tid] = sum / (float)len;
        hid[bid * HV + tid] = hs[tid];
    }
}

// ---------- candidate GRU + attention: one WG/batch, merged phases ----------
// Phases: A(q + rz-hidden + n-hidden) B(tanh q) C(scores) D(exp+sum, no max pass:
// |score| <= sum|v_att| <= 16, exp(16)=8.9e6 fine in fp32) E(ctx) F(ctx finalize)
// G(rz-ctx + n-ctx) H(gate reduce + h update)
__global__ __launch_bounds__(1024) void cand_rnn(
    const float* __restrict__ GI, const int* __restrict__ lens,
    const float* __restrict__ bhh, const __half* __restrict__ WrzH,
    const __half* __restrict__ WnH, const __half* __restrict__ WqH,
    const float* __restrict__ v_att, const __half* __restrict__ AOH,
    const __half* __restrict__ TH, const float* __restrict__ hid,
    float* __restrict__ outp)
{
    __shared__ __align__(16) f16x2 x2[256];   // [h pairs(128); ctx pairs(128)]
    __shared__ __align__(16) float hs[256];
    __shared__ float tqs[256];
    __shared__ float vls[256];
    __shared__ float attn[256];
    __shared__ __align__(16) float redBig[2048];   // q(A) -> scores(C) -> ctx(E) -> rzc+nc(G)
    __shared__ __align__(16) float redRZh[1024];   // A -> H
    __shared__ __align__(16) float redNh[1024];    // A -> H
    __shared__ float bhhS[768];
    __shared__ float wred[8];

    int tid = threadIdx.x;
    int b = blockIdx.x;
    int len = lens[b];

    const f16x2* Wq2  = (const f16x2*)WqH;
    const f16x2* Wrz2 = (const f16x2*)WrzH;
    const f16x2* Wn2  = (const f16x2*)WnH;
    const f16x2* T2   = (const f16x2*)TH + (size_t)b * 256 * 128;
    const f16x2* AO2  = (const f16x2*)AOH + (size_t)b * 256 * 128;

    if (tid < 256) { hs[tid] = hid[b * HV + tid]; vls[tid] = v_att[tid]; }
    if (tid < 768) bhhS[tid] = bhh[tid];
    __syncthreads();
    if (tid < 128) {
        f16x2 v = { (_Float16)hs[2 * tid], (_Float16)hs[2 * tid + 1] };
        x2[tid] = v;
    }
    __syncthreads();

    float csum = 0.f;

    for (int t = 0; t < LCV; ++t) {
        { // A-q: q partials, 4-way k-split (1024 thr x 32 fdot2)
            int m = tid & 255, kc = tid >> 8;
            float a0 = 0.f, a1 = 0.f;
            #pragma unroll 8
            for (int i = 0; i < 32; i += 2) {
                int k2 = kc * 32 + i;
                a0 = __builtin_amdgcn_fdot2(Wq2[k2 * 256 + m], x2[k2], a0, false);
                a1 = __builtin_amdgcn_fdot2(Wq2[(k2 + 1) * 256 + m], x2[k2 + 1], a1, false);
            }
            redBig[kc * 256 + m] = a0 + a1;
        }
        { // A-rzh: rz-gate hidden part, 2-way k-split (1024 thr x 64 fdot2)
            int j = tid & 511, kh2 = tid >> 9;
            float a0 = 0.f, a1 = 0.f;
            #pragma unroll 8
            for (int i = 0; i < 64; i += 2) {
                int kk = kh2 * 64 + i;                 // hidden pairs 0..127
                a0 = __builtin_amdgcn_fdot2(Wrz2[(size_t)kk * 512 + j], x2[kk], a0, false);
                a1 = __builtin_amdgcn_fdot2(Wrz2[(size_t)(kk + 1) * 512 + j], x2[kk + 1], a1, false);
            }
            redRZh[tid] = a0 + a1;
        }
        { // A-nh: n-gate hidden part, 4-way k-split (1024 thr x 32 fdot2)
            int j = tid & 255, q4 = tid >> 8;
            float a0 = 0.f, a1 = 0.f;
            #pragma unroll 8
            for (int i = 0; i < 32; i += 2) {
                int gg = q4 * 32 + i;                  // hidden slots 0..127 -> x2[gg]
                a0 = __builtin_amdgcn_fdot2(Wn2[(size_t)gg * 256 + j], x2[gg], a0, false);
                a1 = __builtin_amdgcn_fdot2(Wn2[(size_t)(gg + 1) * 256 + j], x2[gg + 1], a1, false);
            }
            redNh[tid] = a0 + a1;
        }
        __syncthreads();
        if (tid < 256) { // B: tq = tanh(q)
            float q = redBig[tid] + redBig[256 + tid] + redBig[512 + tid] + redBig[768 + tid];
            tqs[tid] = tanh_(q);
        }
        __syncthreads();
        { // C: score partials: tanh(k+q) = (T+tq)/(1+T*tq)
            int l2 = tid & 127, hg = tid >> 7;
            float s0 = 0.f, s1 = 0.f;
            #pragma unroll 8
            for (int i = 0; i < 32; ++i) {
                int h = hg * 32 + i;
                f16x2 Tv = T2[(size_t)h * 128 + l2];
                float tq = tqs[h], vv = vls[h];
                float T0 = (float)Tv.x, T1 = (float)Tv.y;
                float d0 = fmaxf(fmaf(T0, tq, 1.f), 1e-6f);
                float d1 = fmaxf(fmaf(T1, tq, 1.f), 1e-6f);
                s0 = fmaf(vv * (T0 + tq), rcp_(d0), s0);
                s1 = fmaf(vv * (T1 + tq), rcp_(d1), s1);
            }
            redBig[hg * 256 + 2 * l2] = s0;
            redBig[hg * 256 + 2 * l2 + 1] = s1;
        }
        __syncthreads();
        if (tid < 256) { // D: reduce scores + exp + wave sum (no max pass; |s|<=16)
            float sv = 0.f;
            #pragma unroll
            for (int hg = 0; hg < 8; ++hg) sv += redBig[hg * 256 + tid];
            float e = __expf(sv);
            attn[tid] = e;
            float s = e;
            #pragma unroll
            for (int o = 1; o < 64; o <<= 1) s += __shfl_xor(s, o, 64);
            if ((tid & 63) == 0) wred[4 + (tid >> 6)] = s;
        }
        __syncthreads();
        { // E: ctx partials, 8-way l-split
            int ho2 = tid & 127, lc = tid >> 7;
            float c0 = 0.f, c1 = 0.f;
            #pragma unroll 8
            for (int i = 0; i < 32; ++i) {
                int l = lc * 32 + i;
                f16x2 ao = AO2[(size_t)l * 128 + ho2];
                float w = attn[l];
                c0 = fmaf(w, (float)ao.x, c0);
                c1 = fmaf(w, (float)ao.y, c1);
            }
            redBig[lc * 256 + 2 * ho2] = c0;
            redBig[lc * 256 + 2 * ho2 + 1] = c1;
        }
        __syncthreads();
        if (tid < 128) { // F: finalize ctx pair -> x2[128+]
            float c0 = 0.f, c1 = 0.f;
            #pragma unroll
            for (int lc = 0; lc < 8; ++lc) {
                c0 += redBig[lc * 256 + 2 * tid];
                c1 += redBig[lc * 256 + 2 * tid + 1];
            }
            float rs = rcp_(wred[4] + wred[5] + wred[6] + wred[7]);
            f16x2 v = { (_Float16)(c0 * rs), (_Float16)(c1 * rs) };
            x2[128 + tid] = v;
        }
        __syncthreads();
        { // G-rzc: rz-gate ctx part, 2-way k-split (1024 thr x 64 fdot2)
            int j = tid & 511, kh2 = tid >> 9;
            float a0 = 0.f, a1 = 0.f;
            #pragma unroll 8
            for (int i = 0; i < 64; i += 2) {
                int kk = 128 + kh2 * 64 + i;           // ctx pairs 128..255
                a0 = __builtin_amdgcn_fdot2(Wrz2[(size_t)kk * 512 + j], x2[kk], a0, false);
                a1 = __builtin_amdgcn_fdot2(Wrz2[(size_t)(kk + 1) * 512 + j], x2[kk + 1], a1, false);
            }
            redBig[tid] = a0 + a1;
        }
        { // G-nc: n-gate ctx part, 4-way k-split (1024 thr x 32 fdot2)
            int j = tid & 255, q4 = tid >> 8;
            float a0 = 0.f, a1 = 0.f;
            #pragma unroll 8
            for (int i = 0; i < 32; i += 2) {
                int gg = 128 + q4 * 32 + i;            // ctx slots 128..255 -> x2[gg]
                a0 = __builtin_amdgcn_fdot2(Wn2[(size_t)gg * 256 + j], x2[gg], a0, false);
                a1 = __builtin_amdgcn_fdot2(Wn2[(size_t)(gg + 1) * 256 + j], x2[gg + 1], a1, false);
            }
            redBig[1024 + tid] = a0 + a1;
        }
        __syncthreads();
        if (tid < 256) { // H: gate reduce + GRU update
            const float* gi = GI + ((size_t)t * BB + b) * G3;
            float rr = (redRZh[tid] + redRZh[512 + tid]) + (redBig[tid] + redBig[512 + tid]);
            float zz = (redRZh[256 + tid] + redRZh[768 + tid]) + (redBig[256 + tid] + redBig[768 + tid]);
            float nh = (redNh[tid] + redNh[256 + tid]) + (redNh[512 + tid] + redNh[768 + tid]);
            float nc = (redBig[1024 + tid] + redBig[1280 + tid]) + (redBig[1536 + tid] + redBig[1792 + tid]);
            float r = sigm(gi[tid] + rr + bhhS[tid]);
            float z = sigm(gi[256 + tid] + zz + bhhS[256 + tid]);
            float n = tanh_(gi[512 + tid] + nc + r * (nh + bhhS[512 + tid]));
            float hk = hs[tid];
            float hn = (1.f - z) * n + z * hk;
            float hnew = (len < t) ? hk : hn;        // strict '<' per reference
            hs[tid] = hnew;
            if (t < len) csum += hnew;
            float other = __shfl_xor(hnew, 1, 64);
            if ((tid & 1) == 0) {
                f16x2 v = { (_Float16)hnew, (_Float16)other };
                x2[tid >> 1] = v;
            }
        }
        __syncthreads();
    }
    if (tid < 256) outp[8192 + b * HV + tid] = csum / (float)len;
}

extern "C" void kernel_launch(void* const* d_in, const int* in_sizes, int n_in,
                              void* d_out, int out_size, void* d_ws, size_t ws_size,
                              hipStream_t stream) {
    const int* anchor_input     = (const int*)d_in[0];
    const int* anchor_length    = (const int*)d_in[1];
    const int* candidate_input  = (const int*)d_in[2];
    const int* candidate_length = (const int*)d_in[3];
    const float* emb    = (const float*)d_in[5];
    const float* W_ih_a = (const float*)d_in[6];
    const float* W_hh_a = (const float*)d_in[7];
    const float* b_ih_a = (const float*)d_in[8];
    const float* b_hh_a = (const float*)d_in[9];
    const float* W_ih_c = (const float*)d_in[10];
    const float* W_hh_c = (const float*)d_in[11];
    const float* b_ih_c = (const float*)d_in[12];
    const float* b_hh_c = (const float*)d_in[13];
    const float* Wq     = (const float*)d_in[14];
    const float* Wk     = (const float*)d_in[15];
    const float* v_att  = (const float*)d_in[16];
    float* out = (float*)d_out;

    // workspace layout (float units), ~70.7 MB
    float* ws = (float*)d_ws;
    size_t off = 0;
    float* GI_a  = ws + off; off += (size_t)LAV * BB * G3;     // 6291456
    float* GI_c  = ws + off; off += (size_t)LCV * BB * G3;     // 6291456
    float* AO    = ws + off; off += (size_t)BB * LAV * HV;     // 2097152
    float* hid   = ws + off; off += (size_t)BB * HV;           // 8192
    float* WT_a  = ws + off; off += 300 * 768;                 // 230400
    float* WT_cx = ws + off; off += 300 * 768;                 // 230400
    __half* TH    = (__half*)(ws + off); off += (size_t)BB * HV * LAV / 2;  // [b][h][l2] pairs
    __half* AOH   = (__half*)(ws + off); off += (size_t)BB * LAV * HV / 2;  // [b][l][h] pairs
    __half* WhaRH = (__half*)(ws + off); off += 98304 / 2;
    __half* WhaSH = (__half*)(ws + off); off += 98304 / 2;
    __half* WqH   = (__half*)(ws + off); off += 65536 / 2;
    __half* WrzH  = (__half*)(ws + off); off += 262144 / 2;
    __half* WnH   = (__half*)(ws + off); off += 131072 / 2;

    prep_pack<<<dim3(1024, 7), 256, 0, stream>>>(W_ih_a, W_ih_c, W_hh_a, W_hh_c, Wq,
                                                 WT_a, WT_cx, WhaRH, WhaSH, WqH, WrzH, WnH);
    gemm_tile<0><<<dim3(128, 12), 256, 0, stream>>>(emb, anchor_input, DV, WT_a, DV, G3, b_ih_a, GI_a);
    gemm_tile<0><<<dim3(128, 12), 256, 0, stream>>>(emb, candidate_input, DV, WT_cx, DV, G3, b_ih_c, GI_c);
    anchor_rnn<<<32, 768, 0, stream>>>(GI_a, anchor_length, b_hh_a, WhaRH, WhaSH, AO, AOH, hid, out);
    gemm_tile<1><<<dim3(128, 4), 256, 0, stream>>>(AO, nullptr, HV, Wk, HV, HV, nullptr, (float*)TH);
    cand_rnn<<<32, 1024, 0, stream>>>(GI_c, candidate_length, b_hh_c, WrzH, WnH, WqH,
                                      v_att, AOH, TH, hid, out);
}